// Round 7
// baseline (136.881 us; speedup 1.0000x reference)
//
#include <hip/hip_runtime.h>
#include <hip/hip_bf16.h>

// HyperPatchConv2d: B=2, CIN=COUT=64, H=W=256, FH=FW=16, SC=128, K=3, reflect pad.
// R7 pipeline (2 kernels -- the minimum for prep/wgen -> conv dependency):
//   mega64: (5120 blk x 256t, 33.3 KB LDS -> 4 blk/CU)
//     bid<512:  x fp32 -> xT bf16 channel-last (HBM-heavy, gates only conv).
//     bid>=512: 64m x 64n bf16 GEMM tile with IN-BLOCK staging (R4 idea, R5 geometry):
//       A from fp32 s2w (permute p(m)=co*576+ci*9+tap, f2bf, slot=row^(g&7) swizzle),
//       B from fp32 s (coalesced 4B lane reads, pack, slot=pl^(g&7)).
//       R4's failure modes fixed: 4 blk/CU (was 2), 1/4 the staging VALU per block.
//   conv:   (512 blk x 512t) R6 body: per-tap contiguous 8 KB weight ring via gll16
//           (1x global traffic), waves = (mt co-quarter x ph px-half).
// Evidence trail: R1/R5/R6 work/traffic/occupancy cuts all ~neutral -> only serialization
// moves dur_us (R3: -4us). This removes the last removable launch + gap.

#define C_OUT 64
#define C_IN  64
#define P_TOTAL 36864
#define N_PATCH 512
#define WSTR 72          // shorts per (r,c) cell in conv window LDS (144B)
#define CSTR3 72         // shorts per patch-row in wgen epilogue LDS (144B, 16B-aligned)

typedef __bf16 bf16x8 __attribute__((ext_vector_type(8)));
typedef float  f32x4  __attribute__((ext_vector_type(4)));

__device__ __forceinline__ unsigned short f2bf(float f) {
  unsigned int u = __float_as_uint(f);
  u += 0x7fffu + ((u >> 16) & 1u);   // RTNE on bf16 boundary
  return (unsigned short)(u >> 16);
}
__device__ __forceinline__ unsigned int pack2(float a, float b) {
  return (unsigned int)f2bf(a) | ((unsigned int)f2bf(b) << 16);
}
__device__ __forceinline__ void gll16(const void* g, void* l) {
  __builtin_amdgcn_global_load_lds(
      (const __attribute__((address_space(1))) void*)g,
      (__attribute__((address_space(3))) void*)l, 16, 0, 0);
}

// ---------- k1: bid<512 x->xT prep; bid>=512 wgen 64x64 GEMM tile, in-block staging ----------
__global__ __launch_bounds__(256) void mega64_kernel(
    const float* __restrict__ x,              // fp32 [2][64][256][256]
    const float* __restrict__ s,              // fp32 [2][128][256]   (16x16 patches flattened)
    const float* __restrict__ s2w,            // fp32 [36864][128]
    unsigned short* __restrict__ xT,          // bf16 [2][256][256][64]
    unsigned short* __restrict__ wout)        // bf16 frags [512 patch][36864], offset o == m
{
  __shared__ unsigned short lds[16640];       // 33.3 KB: xl [64][260] | As+Bs (32 KB) | Ct (9 KB)
  const int bid = blockIdx.x;
  const int tid = threadIdx.x;

  if (bid < 512) {                // x-part: block = (bb,row); float4 loads, LDS transpose
    const int bb = bid >> 8, row = bid & 255;
    unsigned short* xl = lds;     // [64][260]
    #pragma unroll
    for (int it = 0; it < 16; ++it) {
      const int ci = it * 4 + (tid >> 6);
      const int px = (tid & 63) * 4;
      const float4 v = *(const float4*)(x + ((size_t)(bb * 64 + ci)) * 65536 + row * 256 + px);
      ushort4 o;
      o.x = f2bf(v.x); o.y = f2bf(v.y); o.z = f2bf(v.z); o.w = f2bf(v.w);
      *(ushort4*)&xl[ci * 260 + px] = o;      // b64 write, ~2-way banks (free)
    }
    __syncthreads();
    unsigned short* dst = xT + ((size_t)((bb << 16) + (row << 8) + tid)) * 64;
    #pragma unroll
    for (int k8 = 0; k8 < 8; ++k8) {          // b16 reads: broadcast-pair, conflict-free
      const unsigned int w0 = (unsigned int)xl[(k8 * 8 + 0) * 260 + tid] |
                              ((unsigned int)xl[(k8 * 8 + 1) * 260 + tid] << 16);
      const unsigned int w1 = (unsigned int)xl[(k8 * 8 + 2) * 260 + tid] |
                              ((unsigned int)xl[(k8 * 8 + 3) * 260 + tid] << 16);
      const unsigned int w2 = (unsigned int)xl[(k8 * 8 + 4) * 260 + tid] |
                              ((unsigned int)xl[(k8 * 8 + 5) * 260 + tid] << 16);
      const unsigned int w3 = (unsigned int)xl[(k8 * 8 + 6) * 260 + tid] |
                              ((unsigned int)xl[(k8 * 8 + 7) * 260 + tid] << 16);
      *(uint4*)(dst + k8 * 8) = make_uint4(w0, w1, w2, w3);
    }
    return;
  }

  // wgen tile: mt in [0,576) 64-m tiles, n in [0,8) 64-n tiles
  const int bid2 = bid - 512;
  const int n = bid2 / 576;
  const int mt = bid2 - n * 576;
  const int m0 = mt * 64;
  const int n0 = n * 64;
  unsigned short* As = lds;          // [16 g][64 slot][8] = 16 KB
  unsigned short* Bs = lds + 8192;   // [16 g][64 slot][8] = 16 KB

  // B staging from s: 1024 tasks (16 g x 64 pl), 4/thread; coalesced 4B lane reads.
  {
    const int sb = n >> 2;                   // batch (n0 = n*64; 64-tiles stay in-batch)
    const int fgbase = (n & 3) * 64;
    #pragma unroll
    for (int i = 0; i < 4; ++i) {
      const int task = i * 256 + tid;
      const int g = task >> 6;
      const int pl = task & 63;
      const int fg = fgbase + pl;
      float v[8];
      #pragma unroll
      for (int e = 0; e < 8; ++e)
        v[e] = s[((size_t)(sb * 128 + g * 8 + e)) * 256 + fg];
      uint4 o;
      o.x = pack2(v[0], v[1]); o.y = pack2(v[2], v[3]);
      o.z = pack2(v[4], v[5]); o.w = pack2(v[6], v[7]);
      const int slot = pl ^ (g & 7);
      *(uint4*)&Bs[g * 512 + slot * 8] = o;
    }
  }
  // A staging from s2w: 256 tasks (64 row x 4 q), 1/thread; row-permute p(m).
  {
    const int row = tid >> 2;
    const int q = tid & 3;
    const int m = m0 + row;
    const int j = m & 7;
    const int lane6 = (m >> 3) & 63;
    const int fragidx = m >> 9;
    const int tap = fragidx >> 3;
    const int ksH = (fragidx >> 2) & 1;
    const int mtH = fragidx & 3;
    const int co = mtH * 16 + (lane6 & 15);
    const int ci = ksH * 32 + (lane6 >> 4) * 8 + j;
    const int p = co * 576 + ci * 9 + tap;
    const float* src = s2w + (size_t)p * 128 + q * 32;
    #pragma unroll
    for (int gg = 0; gg < 4; ++gg) {
      const int g = q * 4 + gg;
      const float4 v0 = *(const float4*)(src + gg * 8);
      const float4 v1 = *(const float4*)(src + gg * 8 + 4);
      uint4 o;
      o.x = pack2(v0.x, v0.y); o.y = pack2(v0.z, v0.w);
      o.z = pack2(v1.x, v1.y); o.w = pack2(v1.z, v1.w);
      const int slot = row ^ (g & 7);
      *(uint4*)&As[g * 512 + slot * 8] = o;
    }
  }
  __syncthreads();

  const int w = tid >> 6;            // wave owns m-rows w*16..w*16+15
  const int lane = tid & 63;
  const int col = lane & 15;
  const int quad = lane >> 4;

  f32x4 acc[4] = {};                 // [nt]
  #pragma unroll
  for (int ks = 0; ks < 4; ++ks) {
    const int g = ks * 4 + quad;
    const int gb = g * 512;
    const int gx = (g & 7) * 8;      // XOR swizzle (low-3-bit row bits only)
    const bf16x8 afr = *(const bf16x8*)&As[gb + (((w * 16 + col) * 8) ^ gx)];
    bf16x8 bfr[4];
    #pragma unroll
    for (int nt = 0; nt < 4; ++nt)
      bfr[nt] = *(const bf16x8*)&Bs[gb + (((nt * 16 + col) * 8) ^ gx)];
    #pragma unroll
    for (int nt = 0; nt < 4; ++nt)
      acc[nt] = __builtin_amdgcn_mfma_f32_16x16x32_bf16(afr, bfr[nt], acc[nt], 0, 0, 0);
  }
  __syncthreads();                   // all A/B frag reads done; lds becomes Ct

  // Epilogue: transpose 64m x 64patch through LDS -> contiguous 128B store per patch
  unsigned short* Ct = lds;          // [64 patch][CSTR3]
  const int mloc = w * 16 + quad * 4;
  #pragma unroll
  for (int nt = 0; nt < 4; ++nt) {
    const int pl = nt * 16 + col;
    ushort4 o;
    o.x = f2bf(acc[nt][0]); o.y = f2bf(acc[nt][1]);
    o.z = f2bf(acc[nt][2]); o.w = f2bf(acc[nt][3]);
    *(ushort4*)&Ct[pl * CSTR3 + mloc] = o;
  }
  __syncthreads();
  #pragma unroll
  for (int i = 0; i < 2; ++i) {
    const int chunk = i * 256 + tid;      // 512: 64 patches x 8 chunks of 16B
    const int pl = chunk >> 3;
    const int ii = chunk & 7;
    const uint4 v = *(const uint4*)&Ct[pl * CSTR3 + ii * 8];
    *(uint4*)(wout + (size_t)(n0 + pl) * P_TOTAL + m0 + ii * 8) = v;
  }
}

// ---------- k2: conv; LDS weight ring (2 taps), wave = (mt co-quarter, ph px-half) ----------
__global__ __launch_bounds__(512, 2) void conv_kernel(
    const unsigned short* __restrict__ xT,     // bf16 [2][256][256][64]
    const unsigned short* __restrict__ wfrag,  // bf16 frags [512][36864]
    float* __restrict__ out)                   // [2][64][256][256]
{
  __shared__ unsigned short lds[23328 + 8192]; // win [324][72] (46.6 KB) | ring [2][4096] (16 KB)
  unsigned short* win = lds;
  unsigned short* ring = lds + 23328;
  const int tid = threadIdx.x;
  const int patch = blockIdx.x;
  const int bb = patch >> 8;
  const int fg = patch & 255;
  const int f = fg >> 4, g = fg & 15;
  const int row0 = f * 16, col0 = g * 16;
  const unsigned short* wp = wfrag + (size_t)patch * P_TOTAL;

  // stage tap-0 weights: contiguous 8 KB (frags tap*8 + ks*4 + mt), 1 gll16/thread
  gll16(wp + tid * 8, ring + tid * 8);

  // stage window (reflect-padded 18x18 cells of 64ci)
  for (int chunk = tid; chunk < 2592; chunk += 512) {
    const int cell = chunk >> 3;
    const int j = chunk & 7;
    const int r = cell / 18;
    const int c = cell - r * 18;
    int rr = row0 + r - 1; rr = rr < 0 ? -rr : (rr > 255 ? 510 - rr : rr);
    int cc = col0 + c - 1; cc = cc < 0 ? -cc : (cc > 255 ? 510 - cc : cc);
    *(uint4*)&win[cell * WSTR + j * 8] =
        *(const uint4*)(xT + ((size_t)((bb << 16) + (rr << 8) + cc)) * 64 + j * 8);
  }
  __syncthreads();   // drains gll16 (vmcnt) + window writes: tap 0 ready

  const int wave = tid >> 6;
  const int lane = tid & 63;
  const int t = lane & 15;
  const int quad = lane >> 4;
  const int mt = wave & 3;        // co-quarter: co = mt*16 + ...
  const int ph = wave >> 2;       // px-half: rows ph*8 + {0..7}

  f32x4 acc[8] = {};              // [nt] -> out row ph*8+nt

  #pragma unroll
  for (int tap = 0; tap < 9; ++tap) {
    if (tap < 8)  // prefetch next tap's 8 KB into the other ring slot; flies under compute
      gll16(wp + (size_t)(tap + 1) * 4096 + tid * 8,
            ring + ((tap + 1) & 1) * 4096 + tid * 8);
    const int cur = (tap & 1) * 4096;
    const int ti = tap / 3;
    const int tj = tap - ti * 3;
    const bf16x8 afr0 = *(const bf16x8*)&ring[cur + mt * 512 + lane * 8];        // ks=0
    const bf16x8 afr1 = *(const bf16x8*)&ring[cur + (4 + mt) * 512 + lane * 8];  // ks=1
    #pragma unroll
    for (int nt = 0; nt < 8; ++nt) {
      const int r = ph * 8 + nt + ti;
      const int c = t + tj;
      const int base = (r * 18 + c) * WSTR + quad * 8;
      const bf16x8 b0 = *(const bf16x8*)&win[base];
      const bf16x8 b1 = *(const bf16x8*)&win[base + 32];
      acc[nt] = __builtin_amdgcn_mfma_f32_16x16x32_bf16(afr0, b0, acc[nt], 0, 0, 0);
      acc[nt] = __builtin_amdgcn_mfma_f32_16x16x32_bf16(afr1, b1, acc[nt], 0, 0, 0);
    }
    __syncthreads();   // ring reads done + next tap's gll16 drained (vmcnt) -> safe swap
  }

  #pragma unroll
  for (int nt = 0; nt < 8; ++nt) {
    const int p = row0 + ph * 8 + nt;
    #pragma unroll
    for (int reg = 0; reg < 4; ++reg) {
      const int co = mt * 16 + quad * 4 + reg;
      out[(((size_t)bb * C_OUT + co) << 16) + ((size_t)p << 8) + col0 + t] = acc[nt][reg];
    }
  }
}

extern "C" void kernel_launch(void* const* d_in, const int* in_sizes, int n_in,
                              void* d_out, int out_size, void* d_ws, size_t ws_size,
                              hipStream_t stream) {
  const float* x   = (const float*)d_in[0];   // [2,64,256,256]
  const float* s   = (const float*)d_in[1];   // [2,128,16,16]
  const float* s2w = (const float*)d_in[2];   // [36864,128]
  float* out = (float*)d_out;

  char* ws = (char*)d_ws;
  unsigned short* wbuf = (unsigned short*)(ws);              // 37,748,736 B
  unsigned short* xT   = (unsigned short*)(ws + 37748736);   // 16,777,216 B (total 54.5 MB)

  mega64_kernel<<<5120, 256, 0, stream>>>(x, s, s2w, xT, wbuf);
  conv_kernel<<<N_PATCH, 512, 0, stream>>>(xT, wbuf, out);
}

// Round 8
// 127.272 us; speedup vs baseline: 1.0755x; 1.0755x over previous
//
#include <hip/hip_runtime.h>
#include <hip/hip_bf16.h>

// HyperPatchConv2d: B=2, CIN=COUT=64, H=W=256, FH=FW=16, SC=128, K=3, reflect pad.
// R8 pipeline (3 kernels; prep/wgen = R5/R6 verified best, conv tap-loop de-barriered):
//   prep_ws:   (608 blk)  s -> sTg, s2w -> s2wP (bf16, fragment-major, XOR-swizzled tiles).
//   wgen_plus: (5120 blk, 33.3 KB LDS, 4 blk/CU) bid<512: x->xT; bid>=512: 64x64 GEMM tile
//              staged via global_load_lds dwordx4 from pre-swizzled buffers.
//   conv:      (512 blk x 512t) per-patch 9-tap MFMA, wave = (mt co-quarter, ph px-half).
//     R8 rework: NO weight ring, NO per-tap barriers. Each wave loads its own 2 frags/tap
//     (16B/lane coalesced from wbuf, L2/L3-resident, 2x redundancy = 75 MB total -- traffic
//     proven free in R1/R6) with +1-tap register prefetch. win is read-only after the initial
//     barrier -> tap loop fully decoupled across waves; latency self-hides at 16 waves/CU.
// R7 lesson: in-block fp32 staging serially gates MFMA regardless of occupancy (45us @ 36%occ
//            vs 42.5us @ 16.5%) -> pre-swizzled gll16 staging is structural, not tunable.
// Session law: only serialization moves dur_us (R3 -4us); work/traffic/occupancy cuts neutral.

#define C_OUT 64
#define C_IN  64
#define P_TOTAL 36864
#define N_PATCH 512
#define WSTR 72          // shorts per (r,c) cell in conv window LDS (144B)
#define CSTR3 72         // shorts per patch-row in wgen epilogue LDS (144B, 16B-aligned)

typedef __bf16 bf16x8 __attribute__((ext_vector_type(8)));
typedef float  f32x4  __attribute__((ext_vector_type(4)));

__device__ __forceinline__ unsigned short f2bf(float f) {
  unsigned int u = __float_as_uint(f);
  u += 0x7fffu + ((u >> 16) & 1u);   // RTNE on bf16 boundary
  return (unsigned short)(u >> 16);
}
__device__ __forceinline__ unsigned int pack2(float a, float b) {
  return (unsigned int)f2bf(a) | ((unsigned int)f2bf(b) << 16);
}
__device__ __forceinline__ void gll16(const void* g, void* l) {
  __builtin_amdgcn_global_load_lds(
      (const __attribute__((address_space(1))) void*)g,
      (__attribute__((address_space(3))) void*)l, 16, 0, 0);
}

// ---------- k1: s -> sTg (blocks 0-31); s2w -> s2wP (blocks 32-607) ----------
__global__ __launch_bounds__(256) void prep_ws(
    const float* __restrict__ s, const float* __restrict__ s2w,
    unsigned short* __restrict__ sTg, unsigned short* __restrict__ s2wP) {
  const int bid = blockIdx.x;
  const int t = threadIdx.x;

  if (bid < 32) {                 // s-part: block = sb*16 + g; thread = patch-in-batch
    const int sb = bid >> 4;
    const int g = bid & 15;
    float v[8];
    #pragma unroll
    for (int e = 0; e < 8; ++e)
      v[e] = s[((size_t)(sb * 128 + g * 8 + e)) * 256 + t];
    uint4 o;
    o.x = pack2(v[0], v[1]); o.y = pack2(v[2], v[3]);
    o.z = pack2(v[4], v[5]); o.w = pack2(v[6], v[7]);
    const int ntile = sb * 2 + (t >> 7);
    const int slot = (t & 127) ^ (g & 7);
    *(uint4*)(sTg + ((size_t)(ntile * 2048 + g * 128 + slot)) * 8) = o;
    return;
  }

  // w-part: thread = quarter-row (m, q). Read s2w[p(m)] coalesced, write swizzled chunks.
  const int b3 = bid - 32;
  const int m = b3 * 64 + (t >> 2);
  const int q = t & 3;
  const int j = m & 7;
  const int lane6 = (m >> 3) & 63;
  const int fragidx = m >> 9;
  const int tap = fragidx >> 3;
  const int ksH = (fragidx >> 2) & 1;
  const int mtH = fragidx & 3;
  const int co = mtH * 16 + (lane6 & 15);
  const int ci = ksH * 32 + (lane6 >> 4) * 8 + j;
  const int p = co * 576 + ci * 9 + tap;
  const float* src = s2w + (size_t)p * 128 + q * 32;
  const int mtile = m >> 7;
  const int r128 = m & 127;
  #pragma unroll
  for (int gg = 0; gg < 4; ++gg) {
    const int g = q * 4 + gg;
    const float4 v0 = *(const float4*)(src + gg * 8);
    const float4 v1 = *(const float4*)(src + gg * 8 + 4);
    uint4 o;
    o.x = pack2(v0.x, v0.y); o.y = pack2(v0.z, v0.w);
    o.z = pack2(v1.x, v1.y); o.w = pack2(v1.z, v1.w);
    const int slot = r128 ^ (g & 7);
    *(uint4*)(s2wP + ((size_t)(mtile * 2048 + g * 128 + slot)) * 8) = o;
  }
}

// ---------- k2: bid<512 x->xT prep; bid>=512 wgen 64x64 GEMM tile ----------
__global__ __launch_bounds__(256) void wgen_plus(
    const float* __restrict__ x,
    const unsigned short* __restrict__ s2wP,  // bf16 swizzled [288 mtile][16 g][128 slot][8]
    const unsigned short* __restrict__ sTg,   // bf16 swizzled [4 ntile][16 g][128 slot][8]
    unsigned short* __restrict__ xT,          // bf16 [2][256][256][64]
    unsigned short* __restrict__ wout)        // bf16 frags [512 patch][36864], offset o == m
{
  __shared__ unsigned short lds[16640];       // 33.3 KB: xl [64][260] | As+Bs (32 KB) | Ct (9 KB)
  const int bid = blockIdx.x;
  const int tid = threadIdx.x;

  if (bid < 512) {                // x-part: block = (bb,row); float4 loads, LDS transpose
    const int bb = bid >> 8, row = bid & 255;
    unsigned short* xl = lds;     // [64][260]
    #pragma unroll
    for (int it = 0; it < 16; ++it) {
      const int ci = it * 4 + (tid >> 6);
      const int px = (tid & 63) * 4;
      const float4 v = *(const float4*)(x + ((size_t)(bb * 64 + ci)) * 65536 + row * 256 + px);
      ushort4 o;
      o.x = f2bf(v.x); o.y = f2bf(v.y); o.z = f2bf(v.z); o.w = f2bf(v.w);
      *(ushort4*)&xl[ci * 260 + px] = o;      // b64 write, ~2-way banks (free)
    }
    __syncthreads();
    unsigned short* dst = xT + ((size_t)((bb << 16) + (row << 8) + tid)) * 64;
    #pragma unroll
    for (int k8 = 0; k8 < 8; ++k8) {          // b16 reads: broadcast-pair, conflict-free
      const unsigned int w0 = (unsigned int)xl[(k8 * 8 + 0) * 260 + tid] |
                              ((unsigned int)xl[(k8 * 8 + 1) * 260 + tid] << 16);
      const unsigned int w1 = (unsigned int)xl[(k8 * 8 + 2) * 260 + tid] |
                              ((unsigned int)xl[(k8 * 8 + 3) * 260 + tid] << 16);
      const unsigned int w2 = (unsigned int)xl[(k8 * 8 + 4) * 260 + tid] |
                              ((unsigned int)xl[(k8 * 8 + 5) * 260 + tid] << 16);
      const unsigned int w3 = (unsigned int)xl[(k8 * 8 + 6) * 260 + tid] |
                              ((unsigned int)xl[(k8 * 8 + 7) * 260 + tid] << 16);
      *(uint4*)(dst + k8 * 8) = make_uint4(w0, w1, w2, w3);
    }
    return;
  }

  // wgen tile: mt in [0,576) 64-m tiles, n in [0,8) 64-n tiles
  const int bid2 = bid - 512;
  const int n = bid2 / 576;
  const int mt = bid2 - n * 576;
  const int m0 = mt * 64;
  const int n0 = n * 64;
  unsigned short* As = lds;          // [16 g][64 slot][8] = 16 KB
  unsigned short* Bs = lds + 8192;   // [16 g][64 slot][8] = 16 KB

  // Half-tile sources: contiguous 512-short (1 KB) segment per g-plane.
  const unsigned short* srcA = s2wP + (size_t)(mt >> 1) * 16384 + (mt & 1) * 512;
  const unsigned short* srcB = sTg + (size_t)(n >> 1) * 16384 + (n & 1) * 512;
  #pragma unroll
  for (int i = 0; i < 4; ++i) {      // A: 1024 chunks of 16B
    const int c = i * 256 + tid;
    const int g = c >> 6;
    gll16(srcA + (size_t)(g * 1024 + (c & 63) * 8), As + c * 8);
  }
  #pragma unroll
  for (int i = 0; i < 4; ++i) {      // B: 1024 chunks of 16B
    const int c = i * 256 + tid;
    const int g = c >> 6;
    gll16(srcB + (size_t)(g * 1024 + (c & 63) * 8), Bs + c * 8);
  }
  __syncthreads();

  const int w = tid >> 6;            // wave owns m-rows w*16..w*16+15
  const int lane = tid & 63;
  const int col = lane & 15;
  const int quad = lane >> 4;

  f32x4 acc[4] = {};                 // [nt]
  #pragma unroll
  for (int ks = 0; ks < 4; ++ks) {
    const int g = ks * 4 + quad;
    const int gb = g * 512;
    const int gx = (g & 7) * 8;      // XOR swizzle (low-3-bit row bits only)
    const bf16x8 afr = *(const bf16x8*)&As[gb + (((w * 16 + col) * 8) ^ gx)];
    bf16x8 bfr[4];
    #pragma unroll
    for (int nt = 0; nt < 4; ++nt)
      bfr[nt] = *(const bf16x8*)&Bs[gb + (((nt * 16 + col) * 8) ^ gx)];
    #pragma unroll
    for (int nt = 0; nt < 4; ++nt)
      acc[nt] = __builtin_amdgcn_mfma_f32_16x16x32_bf16(afr, bfr[nt], acc[nt], 0, 0, 0);
  }
  __syncthreads();                   // all A/B frag reads done; lds becomes Ct

  // Epilogue: transpose 64m x 64patch through LDS -> contiguous 128B store per patch
  unsigned short* Ct = lds;          // [64 patch][CSTR3]
  const int mloc = w * 16 + quad * 4;
  #pragma unroll
  for (int nt = 0; nt < 4; ++nt) {
    const int pl = nt * 16 + col;
    ushort4 o;
    o.x = f2bf(acc[nt][0]); o.y = f2bf(acc[nt][1]);
    o.z = f2bf(acc[nt][2]); o.w = f2bf(acc[nt][3]);
    *(ushort4*)&Ct[pl * CSTR3 + mloc] = o;
  }
  __syncthreads();
  #pragma unroll
  for (int i = 0; i < 2; ++i) {
    const int chunk = i * 256 + tid;      // 512: 64 patches x 8 chunks of 16B
    const int pl = chunk >> 3;
    const int ii = chunk & 7;
    const uint4 v = *(const uint4*)&Ct[pl * CSTR3 + ii * 8];
    *(uint4*)(wout + (size_t)(n0 + pl) * P_TOTAL + m0 + ii * 8) = v;
  }
}

// ---------- k3: conv; barrier-free tap loop, reg-prefetched weights ----------
__global__ __launch_bounds__(512, 2) void conv_kernel(
    const unsigned short* __restrict__ xT,     // bf16 [2][256][256][64]
    const unsigned short* __restrict__ wfrag,  // bf16 frags [512][36864]
    float* __restrict__ out)                   // [2][64][256][256]
{
  __shared__ unsigned short win[324 * WSTR];   // 46656 B (only LDS)
  const int tid = threadIdx.x;
  const int patch = blockIdx.x;
  const int bb = patch >> 8;
  const int fg = patch & 255;
  const int f = fg >> 4, g = fg & 15;
  const int row0 = f * 16, col0 = g * 16;

  // stage window (reflect-padded 18x18 cells of 64ci)
  for (int chunk = tid; chunk < 2592; chunk += 512) {
    const int cell = chunk >> 3;
    const int j = chunk & 7;
    const int r = cell / 18;
    const int c = cell - r * 18;
    int rr = row0 + r - 1; rr = rr < 0 ? -rr : (rr > 255 ? 510 - rr : rr);
    int cc = col0 + c - 1; cc = cc < 0 ? -cc : (cc > 255 ? 510 - cc : cc);
    *(uint4*)&win[cell * WSTR + j * 8] =
        *(const uint4*)(xT + ((size_t)((bb << 16) + (rr << 8) + cc)) * 64 + j * 8);
  }
  __syncthreads();   // win read-only hereafter -> tap loop needs NO barriers

  const int wave = tid >> 6;
  const int lane = tid & 63;
  const int t = lane & 15;
  const int quad = lane >> 4;
  const int mt = wave & 3;        // co-quarter: co = mt*16 + ...
  const int ph = wave >> 2;       // px-half: rows ph*8 + {0..7}

  // wave's weight stream: frag (tap*8 + ks*4 + mt), 16B/lane coalesced, L2/L3-resident
  const bf16x8* wb = (const bf16x8*)(wfrag + (size_t)patch * P_TOTAL);
  f32x4 acc[8] = {};              // [nt] -> out row ph*8+nt

  bf16x8 a0 = wb[(size_t)(mt)*64 + lane];        // tap 0, ks 0
  bf16x8 a1 = wb[(size_t)(4 + mt)*64 + lane];    // tap 0, ks 1

  #pragma unroll
  for (int tap = 0; tap < 9; ++tap) {
    bf16x8 n0, n1;
    if (tap < 8) {  // +1-tap register prefetch; flies under this tap's LDS+MFMA
      n0 = wb[(size_t)((tap + 1) * 8 + mt) * 64 + lane];
      n1 = wb[(size_t)((tap + 1) * 8 + 4 + mt) * 64 + lane];
    }
    const int ti = tap / 3;
    const int tj = tap - ti * 3;
    #pragma unroll
    for (int nt = 0; nt < 8; ++nt) {
      const int r = ph * 8 + nt + ti;
      const int c = t + tj;
      const int base = (r * 18 + c) * WSTR + quad * 8;
      const bf16x8 b0 = *(const bf16x8*)&win[base];
      const bf16x8 b1 = *(const bf16x8*)&win[base + 32];
      acc[nt] = __builtin_amdgcn_mfma_f32_16x16x32_bf16(a0, b0, acc[nt], 0, 0, 0);
      acc[nt] = __builtin_amdgcn_mfma_f32_16x16x32_bf16(a1, b1, acc[nt], 0, 0, 0);
    }
    if (tap < 8) { a0 = n0; a1 = n1; }
  }

  #pragma unroll
  for (int nt = 0; nt < 8; ++nt) {
    const int p = row0 + ph * 8 + nt;
    #pragma unroll
    for (int reg = 0; reg < 4; ++reg) {
      const int co = mt * 16 + quad * 4 + reg;
      out[(((size_t)bb * C_OUT + co) << 16) + ((size_t)p << 8) + col0 + t] = acc[nt][reg];
    }
  }
}

extern "C" void kernel_launch(void* const* d_in, const int* in_sizes, int n_in,
                              void* d_out, int out_size, void* d_ws, size_t ws_size,
                              hipStream_t stream) {
  const float* x   = (const float*)d_in[0];   // [2,64,256,256]
  const float* s   = (const float*)d_in[1];   // [2,128,16,16]
  const float* s2w = (const float*)d_in[2];   // [36864,128]
  float* out = (float*)d_out;

  char* ws = (char*)d_ws;
  unsigned short* wbuf = (unsigned short*)(ws);              // 37,748,736 B
  unsigned short* sTg  = (unsigned short*)(ws + 37748736);   //    131,072 B
  unsigned short* xT   = (unsigned short*)(ws + 37879808);   // 16,777,216 B
  unsigned short* s2wP = (unsigned short*)(ws + 54657024);   //  9,437,184 B (total 64.1 MB)

  prep_ws<<<608, 256, 0, stream>>>(s, s2w, sTg, s2wP);
  wgen_plus<<<5120, 256, 0, stream>>>(x, s2wP, sTg, xT, wbuf);
  conv_kernel<<<N_PATCH, 512, 0, stream>>>(xT, wbuf, out);
}